// Round 6
// baseline (810.724 us; speedup 1.0000x reference)
//
#include <hip/hip_runtime.h>
#include <hip/hip_bf16.h>
#include <math.h>

#define GAMMA 0.1f
#define EPSILON 0.1f
#define NUM_ITERS 4
#define BSHIFT 9           // bucket covers 512 dst nodes
#define LDP 136            // padded LDS row stride (bf16 elems): 272B = 68 dw == 4 mod 32

typedef __attribute__((ext_vector_type(8))) short short8;   // 8 bf16 bit-patterns
typedef __attribute__((ext_vector_type(4))) float floatx4;

__device__ __forceinline__ float bf2f(unsigned short u) {
  union { unsigned int i; float f; } v; v.i = ((unsigned int)u) << 16; return v.f;
}
__device__ __forceinline__ unsigned short f2bf(float f) {
  union { float f; unsigned int i; } v; v.f = f;
  unsigned int x = v.i;
  return (unsigned short)((x + 0x7fffu + ((x >> 16) & 1u)) >> 16);
}
__device__ __forceinline__ unsigned int f2_to_bfx2(float a, float b) {
  return (unsigned int)f2bf(a) | (((unsigned int)f2bf(b)) << 16);
}
__device__ __forceinline__ float2 bfx2_to_f2(unsigned int u) {
  union { unsigned int i; float f; } lo, hi;
  lo.i = u << 16; hi.i = u & 0xffff0000u;
  return make_float2(lo.f, hi.f);
}
__device__ __forceinline__ float tanh_fast(float s) {
  float c = fminf(15.0f, fmaxf(-15.0f, s));
  float e = __expf(2.0f * c);
  return (e - 1.0f) * __frcp_rn(e + 1.0f);
}
__device__ __forceinline__ short8 pack_bf8(float4 f0, float4 f1) {
  union { short8 s; unsigned int u[4]; } pk;
  pk.u[0] = f2_to_bfx2(f0.x, f0.y);
  pk.u[1] = f2_to_bfx2(f0.z, f0.w);
  pk.u[2] = f2_to_bfx2(f1.x, f1.y);
  pk.u[3] = f2_to_bfx2(f1.z, f1.w);
  return pk.s;
}

// ------------------------------------------------------------- dtype detect

__global__ void detect_kernel(const unsigned int* __restrict__ x, int* __restrict__ flag) {
  __shared__ int ws4[4];
  int tid = threadIdx.x;
  int bad = 0;
  for (int i = tid; i < 2048; i += 256) {
    unsigned int u = x[i];
    float lo = bf2f((unsigned short)(u & 0xffffu));
    if (!(fabsf(lo) <= 64.0f)) bad++;
  }
#pragma unroll
  for (int d = 1; d < 64; d <<= 1) bad += __shfl_xor(bad, d, 64);
  if ((tid & 63) == 0) ws4[tid >> 6] = bad;
  __syncthreads();
  if (tid == 0) *flag = (ws4[0] + ws4[1] + ws4[2] + ws4[3] > 64) ? 1 : 0;
}

// ------------------------------------------------------------- setup

__global__ void fill_kernel(unsigned short* __restrict__ out, int n, unsigned short val) {
  int t = blockIdx.x * blockDim.x + threadIdx.x;
  if (t < n) out[t] = val;
}

__global__ void prep_kernel(const void* __restrict__ Wv, const void* __restrict__ Wphiv,
                            const void* __restrict__ biasv, const int* __restrict__ flag,
                            unsigned short* __restrict__ Am, unsigned short* __restrict__ Wb,
                            float* __restrict__ bias_f) {
  int t = blockIdx.x * blockDim.x + threadIdx.x;
  if (t >= 128 * 128) return;
  int isf = *flag;
  int j = t >> 7, k = t & 127;
  float w_jk, w_kj, wp;
  if (isf) {
    const float* W = (const float*)Wv;
    const float* Wp = (const float*)Wphiv;
    w_jk = W[t]; w_kj = W[k * 128 + j]; wp = Wp[t];
  } else {
    const unsigned short* W = (const unsigned short*)Wv;
    const unsigned short* Wp = (const unsigned short*)Wphiv;
    w_jk = bf2f(W[t]); w_kj = bf2f(W[k * 128 + j]); wp = bf2f(Wp[t]);
  }
  float v = w_jk - w_kj;
  if (j == k) v -= GAMMA;
  Am[t] = f2bf(v);
  Wb[t] = f2bf(wp);
  if (t < 128)
    bias_f[t] = isf ? ((const float*)biasv)[t] : bf2f(((const unsigned short*)biasv)[t]);
}

__global__ void init_x_kernel(const void* __restrict__ xinv, const int* __restrict__ flag,
                              float* __restrict__ xf32, int N, int NP) {
  int t = blockIdx.x * blockDim.x + threadIdx.x;
  if (t >= NP * 32) return;
  int base = t * 4;
  int row = base >> 7;
  float4 o;
  if (row < N) {
    if (*flag) {
      o = *(const float4*)((const float*)xinv + base);
    } else {
      uint2 v = *(const uint2*)((const unsigned short*)xinv + base);
      float2 f0 = bfx2_to_f2(v.x), f1 = bfx2_to_f2(v.y);
      o = make_float4(f0.x, f0.y, f1.x, f1.y);
    }
  } else {
    o = make_float4(0.f, 0.f, 0.f, 0.f);
  }
  *(float4*)(xf32 + base) = o;
}

// -------------------- bucketed CSR build --------------

__global__ void bcount_kernel(const int* __restrict__ dst, int* __restrict__ gcnt,
                              int E, int NB) {
  __shared__ int cnt[512];
  int tid = threadIdx.x;
  for (int j = tid; j < 512; j += 256) cnt[j] = 0;
  __syncthreads();
  int base = blockIdx.x * 4096;
#pragma unroll
  for (int k = 0; k < 16; ++k) {
    int i = base + k * 256 + tid;
    if (i < E) atomicAdd(&cnt[dst[i] >> BSHIFT], 1);
  }
  __syncthreads();
  for (int j = tid; j < NB; j += 256)
    if (cnt[j]) atomicAdd(&gcnt[j], cnt[j]);
}

__global__ void bscan_kernel(const int* __restrict__ gcnt, int* __restrict__ gofs,
                             int* __restrict__ gcur, int NB, int E) {
  if (threadIdx.x == 0 && blockIdx.x == 0) {
    int run = 0;
    for (int i = 0; i < NB; ++i) { gofs[i] = run; gcur[i] = run; run += gcnt[i]; }
    gofs[NB] = E;
  }
}

__global__ void bscatter_kernel(const int* __restrict__ src, const int* __restrict__ dst,
                                int* __restrict__ gcur, uint2* __restrict__ bpairs,
                                int E, int NB) {
  __shared__ int cnt[512];
  __shared__ int pos[512];
  int tid = threadIdx.x;
  for (int j = tid; j < 512; j += 256) cnt[j] = 0;
  __syncthreads();
  int base = blockIdx.x * 4096;
#pragma unroll
  for (int k = 0; k < 16; ++k) {
    int i = base + k * 256 + tid;
    if (i < E) atomicAdd(&cnt[dst[i] >> BSHIFT], 1);
  }
  __syncthreads();
  for (int j = tid; j < NB; j += 256)
    pos[j] = cnt[j] ? atomicAdd(&gcur[j], cnt[j]) : 0;
  __syncthreads();
#pragma unroll
  for (int k = 0; k < 16; ++k) {
    int i = base + k * 256 + tid;
    if (i < E) {
      int d = dst[i];
      int slot = atomicAdd(&pos[d >> BSHIFT], 1);
      bpairs[slot] = make_uint2((unsigned)d, (unsigned)src[i]);
    }
  }
}

__global__ __launch_bounds__(256) void bfinal_kernel(
    const uint2* __restrict__ bpairs, const int* __restrict__ gofs,
    int* __restrict__ offs, float* __restrict__ dinv, int* __restrict__ csr,
    int N, int NP, int E) {
  __shared__ int dl[512];
  __shared__ int cur[512];
  __shared__ int wsum2[4];
  int b = blockIdx.x, t = threadIdx.x;
  int node0 = b << BSHIFT;
  dl[t] = 0; dl[t + 256] = 0;
  __syncthreads();
  int e0 = gofs[b], e1 = gofs[b + 1];
  for (int i = e0 + t; i < e1; i += 256)
    atomicAdd(&dl[bpairs[i].x - node0], 1);
  __syncthreads();
  int v0 = dl[2 * t], v1 = dl[2 * t + 1];
  int ps = v0 + v1;
  int lane = t & 63, w = t >> 6;
  int inc = ps;
#pragma unroll
  for (int d = 1; d < 64; d <<= 1) { int q = __shfl_up(inc, d, 64); if (lane >= d) inc += q; }
  if (lane == 63) wsum2[w] = inc;
  __syncthreads();
  int woff = 0;
  for (int k = 0; k < w; ++k) woff += wsum2[k];
  int base = e0 + woff + inc - ps;
  int n0 = node0 + 2 * t, n1 = node0 + 2 * t + 1;
  if (n0 < N) offs[n0] = base;
  if (n1 < N) offs[n1] = base + v0;
  if (n0 < NP) dinv[n0] = rsqrtf((float)v0 + 1.0f);
  if (n1 < NP) dinv[n1] = rsqrtf((float)v1 + 1.0f);
  cur[2 * t] = base;
  cur[2 * t + 1] = base + v0;
  if (b == 0 && t == 0) offs[N] = E;
  __syncthreads();
  for (int i = e0 + t; i < e1; i += 256) {
    uint2 p = bpairs[i];
    int s = atomicAdd(&cur[p.x - node0], 1);
    csr[s] = (int)p.y;
  }
}

// ------------------------------------------------------------- per-iteration

// iter-0 only: y = bf16( (x@Wphi^T) * dinv[row] ). Direct-global GEMM, no LDS.
__global__ __launch_bounds__(256) void gemm0_kernel(
    const float* __restrict__ xf32, const unsigned short* __restrict__ Bmat,
    const float* __restrict__ dinv, unsigned short* __restrict__ ybuf) {
  const int tid = threadIdx.x, lane = tid & 63, wid = tid >> 6;
  const int l15 = lane & 15, quad = lane >> 4;
  const int m0 = blockIdx.x * 64;
  const int arow = m0 + wid * 16 + l15;

  short8 afrag[4];
#pragma unroll
  for (int kk = 0; kk < 4; ++kk) {
    const float* p = xf32 + (size_t)arow * 128 + kk * 32 + quad * 8;
    afrag[kk] = pack_bf8(*(const float4*)p, *(const float4*)(p + 4));
  }
  floatx4 acc[8];
  const floatx4 zero = {0.f, 0.f, 0.f, 0.f};
#pragma unroll
  for (int j = 0; j < 8; ++j) acc[j] = zero;
#pragma unroll
  for (int kk = 0; kk < 4; ++kk) {
    const int koff = kk * 32 + quad * 8;
#pragma unroll
    for (int j = 0; j < 8; ++j) {
      short8 b = *(const short8*)(Bmat + (j * 16 + l15) * 128 + koff);
      acc[j] = __builtin_amdgcn_mfma_f32_16x16x32_bf16(afrag[kk], b, acc[j], 0, 0, 0);
    }
  }
#pragma unroll
  for (int r = 0; r < 4; ++r) {
    int row = m0 + wid * 16 + quad * 4 + r;
    float dv = dinv[row];
#pragma unroll
    for (int j = 0; j < 8; ++j)
      ybuf[(size_t)row * 128 + j * 16 + l15] = f2bf(acc[j][r] * dv);
  }
}

// fused update, direct-global GEMM:
//   s = x@Am^T + g + bias; h=tanh(s); x' = x + eps*h (f32 state, guarded write);
//   optional out write (f32/bf16 per flag); if ybuf: y' = bf16((x'@Wphi^T)*dinv)
//   via LDS transpose (padded rows -> 2-way bank aliasing only).
__global__ __launch_bounds__(256) void fused_kernel(
    float* __restrict__ xf32, const unsigned short* __restrict__ Am,
    const unsigned short* __restrict__ Wphi, const float* __restrict__ dinv,
    const unsigned short* __restrict__ g, const float* __restrict__ bias_f,
    void* __restrict__ outb, unsigned short* __restrict__ ybuf,
    const int* __restrict__ flag, int Mvalid) {
  __shared__ unsigned short xs[64 * LDP];   // 17408 B
  const int tid = threadIdx.x, lane = tid & 63, wid = tid >> 6;
  const int l15 = lane & 15, quad = lane >> 4;
  const int m0 = blockIdx.x * 64;
  const int arow = m0 + wid * 16 + l15;

  short8 afrag[4];
#pragma unroll
  for (int kk = 0; kk < 4; ++kk) {
    const float* p = xf32 + (size_t)arow * 128 + kk * 32 + quad * 8;
    afrag[kk] = pack_bf8(*(const float4*)p, *(const float4*)(p + 4));
  }
  floatx4 acc[8];
  const floatx4 zero = {0.f, 0.f, 0.f, 0.f};
#pragma unroll
  for (int j = 0; j < 8; ++j) acc[j] = zero;
#pragma unroll
  for (int kk = 0; kk < 4; ++kk) {
    const int koff = kk * 32 + quad * 8;
#pragma unroll
    for (int j = 0; j < 8; ++j) {
      short8 b = *(const short8*)(Am + (j * 16 + l15) * 128 + koff);
      acc[j] = __builtin_amdgcn_mfma_f32_16x16x32_bf16(afrag[kk], b, acc[j], 0, 0, 0);
    }
  }

  float bcol[8];
#pragma unroll
  for (int j = 0; j < 8; ++j) bcol[j] = bias_f[j * 16 + l15];

  const int isf = *flag;
  // epilogue: C/D layout col=lane&15, row=(lane>>4)*4+reg; compute all
  // (pad rows read initialized pad xf32 / poisoned-but-finite g), guard writes.
#pragma unroll
  for (int r = 0; r < 4; ++r) {
    int row = m0 + wid * 16 + quad * 4 + r;
    bool valid = row < Mvalid;
    int lrow = wid * 16 + quad * 4 + r;
#pragma unroll
    for (int j = 0; j < 8; ++j) {
      int col = j * 16 + l15;
      size_t idx = (size_t)row * 128 + col;
      float s = acc[j][r] + bf2f(g[idx]) + bcol[j];
      float h = tanh_fast(s);
      float x = xf32[idx] + EPSILON * h;
      if (ybuf) xs[lrow * LDP + col] = f2bf(x);
      if (valid) {
        xf32[idx] = x;
        if (outb) {
          if (isf) ((float*)outb)[idx] = x;
          else     ((unsigned short*)outb)[idx] = f2bf(x);
        }
      }
    }
  }

  if (ybuf) {
    __syncthreads();
    short8 a2[4];
#pragma unroll
    for (int kk = 0; kk < 4; ++kk)
      a2[kk] = *(const short8*)&xs[(wid * 16 + l15) * LDP + kk * 32 + quad * 8];
    floatx4 acc2[8];
#pragma unroll
    for (int j = 0; j < 8; ++j) acc2[j] = zero;
#pragma unroll
    for (int kk = 0; kk < 4; ++kk) {
      const int koff = kk * 32 + quad * 8;
#pragma unroll
      for (int j = 0; j < 8; ++j) {
        short8 b = *(const short8*)(Wphi + (j * 16 + l15) * 128 + koff);
        acc2[j] = __builtin_amdgcn_mfma_f32_16x16x32_bf16(a2[kk], b, acc2[j], 0, 0, 0);
      }
    }
#pragma unroll
    for (int r = 0; r < 4; ++r) {
      int row = m0 + wid * 16 + quad * 4 + r;
      float dv = dinv[row];
#pragma unroll
      for (int j = 0; j < 8; ++j)
        ybuf[(size_t)row * 128 + j * 16 + l15] = f2bf(acc2[j][r] * dv);
    }
  }
}

// one wave per node, quad-per-edge gather
__global__ __launch_bounds__(256) void agg_kernel(
    const unsigned short* __restrict__ y,
    const int* __restrict__ offs,
    const int* __restrict__ csr,
    const float* __restrict__ dinv,
    unsigned short* __restrict__ g,
    int N) {
  int i = blockIdx.x * 4 + (threadIdx.x >> 6);
  if (i >= N) return;
  int lane = threadIdx.x & 63;
  int sub = lane >> 4;
  int c8 = (lane & 15) * 8;

  float a0 = 0.f, a1 = 0.f, a2 = 0.f, a3 = 0.f, a4 = 0.f, a5 = 0.f, a6 = 0.f, a7 = 0.f;

  int e0 = offs[i], e1 = offs[i + 1];
  int e = e0 + sub;
  for (; e + 4 < e1; e += 8) {
    int s0 = csr[e];
    int s1 = csr[e + 4];
    uint4 u0 = *(const uint4*)(y + (size_t)s0 * 128 + c8);
    uint4 u1 = *(const uint4*)(y + (size_t)s1 * 128 + c8);
    float2 f;
    f = bfx2_to_f2(u0.x); a0 += f.x; a1 += f.y;
    f = bfx2_to_f2(u0.y); a2 += f.x; a3 += f.y;
    f = bfx2_to_f2(u0.z); a4 += f.x; a5 += f.y;
    f = bfx2_to_f2(u0.w); a6 += f.x; a7 += f.y;
    f = bfx2_to_f2(u1.x); a0 += f.x; a1 += f.y;
    f = bfx2_to_f2(u1.y); a2 += f.x; a3 += f.y;
    f = bfx2_to_f2(u1.z); a4 += f.x; a5 += f.y;
    f = bfx2_to_f2(u1.w); a6 += f.x; a7 += f.y;
  }
  if (e < e1) {
    int s0 = csr[e];
    uint4 u0 = *(const uint4*)(y + (size_t)s0 * 128 + c8);
    float2 f;
    f = bfx2_to_f2(u0.x); a0 += f.x; a1 += f.y;
    f = bfx2_to_f2(u0.y); a2 += f.x; a3 += f.y;
    f = bfx2_to_f2(u0.z); a4 += f.x; a5 += f.y;
    f = bfx2_to_f2(u0.w); a6 += f.x; a7 += f.y;
  }

  a0 += __shfl_xor(a0, 16, 64); a0 += __shfl_xor(a0, 32, 64);
  a1 += __shfl_xor(a1, 16, 64); a1 += __shfl_xor(a1, 32, 64);
  a2 += __shfl_xor(a2, 16, 64); a2 += __shfl_xor(a2, 32, 64);
  a3 += __shfl_xor(a3, 16, 64); a3 += __shfl_xor(a3, 32, 64);
  a4 += __shfl_xor(a4, 16, 64); a4 += __shfl_xor(a4, 32, 64);
  a5 += __shfl_xor(a5, 16, 64); a5 += __shfl_xor(a5, 32, 64);
  a6 += __shfl_xor(a6, 16, 64); a6 += __shfl_xor(a6, 32, 64);
  a7 += __shfl_xor(a7, 16, 64); a7 += __shfl_xor(a7, 32, 64);

  if (sub == 0) {
    uint4 su = *(const uint4*)(y + (size_t)i * 128 + c8);
    float2 f;
    f = bfx2_to_f2(su.x); a0 += f.x; a1 += f.y;
    f = bfx2_to_f2(su.y); a2 += f.x; a3 += f.y;
    f = bfx2_to_f2(su.z); a4 += f.x; a5 += f.y;
    f = bfx2_to_f2(su.w); a6 += f.x; a7 += f.y;
    float dv = dinv[i];
    uint4 o;
    o.x = f2_to_bfx2(a0 * dv, a1 * dv);
    o.y = f2_to_bfx2(a2 * dv, a3 * dv);
    o.z = f2_to_bfx2(a4 * dv, a5 * dv);
    o.w = f2_to_bfx2(a6 * dv, a7 * dv);
    *(uint4*)(g + (size_t)i * 128 + c8) = o;
  }
}

// ------------------------------------------------------------- launch

extern "C" void kernel_launch(void* const* d_in, const int* in_sizes, int n_in,
                              void* d_out, int out_size, void* d_ws, size_t ws_size,
                              hipStream_t stream) {
  const void* x_in = d_in[0];
  const int* ei = (const int*)d_in[1];
  const void* W = d_in[2];
  const void* Wphi = d_in[3];
  const void* bias = d_in[4];

  const int N = in_sizes[0] / 128;
  const int E = in_sizes[1] / 2;
  const int NP = ((N + 63) / 64) * 64;
  const int* src = ei;
  const int* dst = ei + E;
  const int NB = (N + 511) >> BSHIFT;
  const int EB = (E + 4095) / 4096;

  size_t off = 0;
  auto place = [&](size_t bytes) { size_t r = off; off = (off + bytes + 255) & ~(size_t)255; return r; };
  size_t o_xf32 = place((size_t)NP * 128 * 4);
  size_t o_y    = place((size_t)NP * 128 * 2);
  size_t o_g    = place((size_t)NP * 128 * 2);
  size_t o_Am   = place(128 * 128 * 2);
  size_t o_Wb   = place(128 * 128 * 2);
  size_t o_bf   = place(128 * 4);
  size_t o_flag = place(4);
  size_t o_dinv = place((size_t)(NB * 512 + 64) * 4);
  size_t o_offs = place((size_t)(N + 1) * 4);
  size_t o_gcnt = place((size_t)NB * 4);
  size_t o_gofs = place((size_t)(NB + 1) * 4);
  size_t o_gcur = place((size_t)NB * 4);
  size_t o_bprs = place((size_t)E * 8);
  size_t o_csr  = place((size_t)E * 4);
  if (off > ws_size || in_sizes[0] % 128 != 0 || out_size != N * 128 || n_in < 5) {
    fill_kernel<<<(out_size * 2 + 255) / 256, 256, 0, stream>>>(
        (unsigned short*)d_out, out_size, (unsigned short)0x3F80);
    return;
  }
  char* basep = (char*)d_ws;
  float* xf32 = (float*)(basep + o_xf32);
  unsigned short* y  = (unsigned short*)(basep + o_y);
  unsigned short* g  = (unsigned short*)(basep + o_g);
  unsigned short* Am = (unsigned short*)(basep + o_Am);
  unsigned short* Wb = (unsigned short*)(basep + o_Wb);
  float* bias_f = (float*)(basep + o_bf);
  int* flag   = (int*)(basep + o_flag);
  float* dinv = (float*)(basep + o_dinv);
  int* offs   = (int*)(basep + o_offs);
  int* gcnt   = (int*)(basep + o_gcnt);
  int* gofs   = (int*)(basep + o_gofs);
  int* gcur   = (int*)(basep + o_gcur);
  uint2* bpairs = (uint2*)(basep + o_bprs);
  int* csr    = (int*)(basep + o_csr);

  hipMemsetAsync(gcnt, 0, (size_t)NB * 4, stream);
  detect_kernel<<<1, 256, 0, stream>>>((const unsigned int*)x_in, flag);
  prep_kernel<<<(128 * 128 + 255) / 256, 256, 0, stream>>>(W, Wphi, bias, flag, Am, Wb, bias_f);
  init_x_kernel<<<(NP * 32 + 255) / 256, 256, 0, stream>>>(x_in, flag, xf32, N, NP);
  bcount_kernel<<<EB, 256, 0, stream>>>(dst, gcnt, E, NB);
  bscan_kernel<<<1, 64, 0, stream>>>(gcnt, gofs, gcur, NB, E);
  bscatter_kernel<<<EB, 256, 0, stream>>>(src, dst, gcur, bpairs, E, NB);
  bfinal_kernel<<<NB, 256, 0, stream>>>(bpairs, gofs, offs, dinv, csr, N, NP, E);

  const int gblocks = NP / 64;
  gemm0_kernel<<<gblocks, 256, 0, stream>>>(xf32, Wb, dinv, y);
  for (int t = 0; t < NUM_ITERS; ++t) {
    agg_kernel<<<(N + 3) / 4, 256, 0, stream>>>(y, offs, csr, dinv, g, N);
    void* outp = (t == NUM_ITERS - 1) ? d_out : nullptr;
    unsigned short* ynext = (t == NUM_ITERS - 1) ? nullptr : y;
    fused_kernel<<<gblocks, 256, 0, stream>>>(xf32, Am, Wb, dinv, g, bias_f,
                                              outp, ynext, flag, N);
  }
}

// Round 7
// 715.619 us; speedup vs baseline: 1.1329x; 1.1329x over previous
//
#include <hip/hip_runtime.h>
#include <hip/hip_bf16.h>
#include <math.h>

#define GAMMA 0.1f
#define EPSILON 0.1f
#define NUM_ITERS 4
#define BSHIFT 9           // bucket covers 512 dst nodes
#define ALDP 132           // f32 acc LDS row stride: 528B, 16B-aligned, ==4 mod 32 banks

typedef __attribute__((ext_vector_type(8))) short short8;   // 8 bf16 bit-patterns
typedef __attribute__((ext_vector_type(4))) float floatx4;

__device__ __forceinline__ float bf2f(unsigned short u) {
  union { unsigned int i; float f; } v; v.i = ((unsigned int)u) << 16; return v.f;
}
__device__ __forceinline__ unsigned short f2bf(float f) {
  union { float f; unsigned int i; } v; v.f = f;
  unsigned int x = v.i;
  return (unsigned short)((x + 0x7fffu + ((x >> 16) & 1u)) >> 16);
}
__device__ __forceinline__ unsigned int f2_to_bfx2(float a, float b) {
  return (unsigned int)f2bf(a) | (((unsigned int)f2bf(b)) << 16);
}
__device__ __forceinline__ float2 bfx2_to_f2(unsigned int u) {
  union { unsigned int i; float f; } lo, hi;
  lo.i = u << 16; hi.i = u & 0xffff0000u;
  return make_float2(lo.f, hi.f);
}
__device__ __forceinline__ float tanh_fast(float s) {
  float c = fminf(15.0f, fmaxf(-15.0f, s));
  float e = __expf(2.0f * c);
  return (e - 1.0f) * __frcp_rn(e + 1.0f);
}

// ------------------------------------------------------------- dtype detect

__global__ void detect_kernel(const unsigned int* __restrict__ x, int* __restrict__ flag) {
  __shared__ int ws4[4];
  int tid = threadIdx.x;
  int bad = 0;
  for (int i = tid; i < 2048; i += 256) {
    unsigned int u = x[i];
    float lo = bf2f((unsigned short)(u & 0xffffu));
    if (!(fabsf(lo) <= 64.0f)) bad++;
  }
#pragma unroll
  for (int d = 1; d < 64; d <<= 1) bad += __shfl_xor(bad, d, 64);
  if ((tid & 63) == 0) ws4[tid >> 6] = bad;
  __syncthreads();
  if (tid == 0) *flag = (ws4[0] + ws4[1] + ws4[2] + ws4[3] > 64) ? 1 : 0;
}

// ------------------------------------------------------------- setup

__global__ void fill_kernel(unsigned short* __restrict__ out, int n, unsigned short val) {
  int t = blockIdx.x * blockDim.x + threadIdx.x;
  if (t < n) out[t] = val;
}

__global__ void prep_kernel(const void* __restrict__ Wv, const void* __restrict__ Wphiv,
                            const void* __restrict__ biasv, const int* __restrict__ flag,
                            unsigned short* __restrict__ Am, unsigned short* __restrict__ Wb,
                            float* __restrict__ bias_f) {
  int t = blockIdx.x * blockDim.x + threadIdx.x;
  if (t >= 128 * 128) return;
  int isf = *flag;
  int j = t >> 7, k = t & 127;
  float w_jk, w_kj, wp;
  if (isf) {
    const float* W = (const float*)Wv;
    const float* Wp = (const float*)Wphiv;
    w_jk = W[t]; w_kj = W[k * 128 + j]; wp = Wp[t];
  } else {
    const unsigned short* W = (const unsigned short*)Wv;
    const unsigned short* Wp = (const unsigned short*)Wphiv;
    w_jk = bf2f(W[t]); w_kj = bf2f(W[k * 128 + j]); wp = bf2f(Wp[t]);
  }
  float v = w_jk - w_kj;
  if (j == k) v -= GAMMA;
  Am[t] = f2bf(v);
  Wb[t] = f2bf(wp);
  if (t < 128)
    bias_f[t] = isf ? ((const float*)biasv)[t] : bf2f(((const unsigned short*)biasv)[t]);
}

// xb <- bf16(x_in), pad rows zero. One thread per 8 elements.
__global__ void init_x_kernel(const void* __restrict__ xinv, const int* __restrict__ flag,
                              unsigned short* __restrict__ xb, int N, int NP) {
  int t = blockIdx.x * blockDim.x + threadIdx.x;
  if (t >= NP * 16) return;
  int base = t * 8;
  int row = base >> 7;
  uint4 o;
  if (row < N) {
    if (*flag) {
      const float* p = (const float*)xinv + base;
      float4 f0 = *(const float4*)p;
      float4 f1 = *(const float4*)(p + 4);
      o.x = f2_to_bfx2(f0.x, f0.y); o.y = f2_to_bfx2(f0.z, f0.w);
      o.z = f2_to_bfx2(f1.x, f1.y); o.w = f2_to_bfx2(f1.z, f1.w);
    } else {
      o = *(const uint4*)((const unsigned short*)xinv + base);
    }
  } else {
    o = make_uint4(0u, 0u, 0u, 0u);
  }
  *(uint4*)(xb + base) = o;
}

// -------------------- bucketed CSR build --------------

__global__ void bcount_kernel(const int* __restrict__ dst, int* __restrict__ gcnt,
                              int E, int NB) {
  __shared__ int cnt[512];
  int tid = threadIdx.x;
  for (int j = tid; j < 512; j += 256) cnt[j] = 0;
  __syncthreads();
  int base = blockIdx.x * 4096;
#pragma unroll
  for (int k = 0; k < 16; ++k) {
    int i = base + k * 256 + tid;
    if (i < E) atomicAdd(&cnt[dst[i] >> BSHIFT], 1);
  }
  __syncthreads();
  for (int j = tid; j < NB; j += 256)
    if (cnt[j]) atomicAdd(&gcnt[j], cnt[j]);
}

__global__ void bscan_kernel(const int* __restrict__ gcnt, int* __restrict__ gofs,
                             int* __restrict__ gcur, int NB, int E) {
  if (threadIdx.x == 0 && blockIdx.x == 0) {
    int run = 0;
    for (int i = 0; i < NB; ++i) { gofs[i] = run; gcur[i] = run; run += gcnt[i]; }
    gofs[NB] = E;
  }
}

__global__ void bscatter_kernel(const int* __restrict__ src, const int* __restrict__ dst,
                                int* __restrict__ gcur, uint2* __restrict__ bpairs,
                                int E, int NB) {
  __shared__ int cnt[512];
  __shared__ int pos[512];
  int tid = threadIdx.x;
  for (int j = tid; j < 512; j += 256) cnt[j] = 0;
  __syncthreads();
  int base = blockIdx.x * 4096;
#pragma unroll
  for (int k = 0; k < 16; ++k) {
    int i = base + k * 256 + tid;
    if (i < E) atomicAdd(&cnt[dst[i] >> BSHIFT], 1);
  }
  __syncthreads();
  for (int j = tid; j < NB; j += 256)
    pos[j] = cnt[j] ? atomicAdd(&gcur[j], cnt[j]) : 0;
  __syncthreads();
#pragma unroll
  for (int k = 0; k < 16; ++k) {
    int i = base + k * 256 + tid;
    if (i < E) {
      int d = dst[i];
      int slot = atomicAdd(&pos[d >> BSHIFT], 1);
      bpairs[slot] = make_uint2((unsigned)d, (unsigned)src[i]);
    }
  }
}

__global__ __launch_bounds__(256) void bfinal_kernel(
    const uint2* __restrict__ bpairs, const int* __restrict__ gofs,
    int* __restrict__ offs, float* __restrict__ dinv, int* __restrict__ csr,
    int N, int NP, int E) {
  __shared__ int dl[512];
  __shared__ int cur[512];
  __shared__ int wsum2[4];
  int b = blockIdx.x, t = threadIdx.x;
  int node0 = b << BSHIFT;
  dl[t] = 0; dl[t + 256] = 0;
  __syncthreads();
  int e0 = gofs[b], e1 = gofs[b + 1];
  for (int i = e0 + t; i < e1; i += 256)
    atomicAdd(&dl[bpairs[i].x - node0], 1);
  __syncthreads();
  int v0 = dl[2 * t], v1 = dl[2 * t + 1];
  int ps = v0 + v1;
  int lane = t & 63, w = t >> 6;
  int inc = ps;
#pragma unroll
  for (int d = 1; d < 64; d <<= 1) { int q = __shfl_up(inc, d, 64); if (lane >= d) inc += q; }
  if (lane == 63) wsum2[w] = inc;
  __syncthreads();
  int woff = 0;
  for (int k = 0; k < w; ++k) woff += wsum2[k];
  int base = e0 + woff + inc - ps;
  int n0 = node0 + 2 * t, n1 = node0 + 2 * t + 1;
  if (n0 < N) offs[n0] = base;
  if (n1 < N) offs[n1] = base + v0;
  if (n0 < NP) dinv[n0] = rsqrtf((float)v0 + 1.0f);
  if (n1 < NP) dinv[n1] = rsqrtf((float)v1 + 1.0f);
  cur[2 * t] = base;
  cur[2 * t + 1] = base + v0;
  if (b == 0 && t == 0) offs[N] = E;
  __syncthreads();
  for (int i = e0 + t; i < e1; i += 256) {
    uint2 p = bpairs[i];
    int s = atomicAdd(&cur[p.x - node0], 1);
    csr[s] = (int)p.y;
  }
}

// ------------------------------------------------------------- per-iteration

// iter-0 only: y = bf16( (x@Wphi^T) * dinv[row] ). Direct-global, no LDS.
__global__ __launch_bounds__(256) void gemm0_kernel(
    const unsigned short* __restrict__ xb, const unsigned short* __restrict__ Bmat,
    const float* __restrict__ dinv, unsigned short* __restrict__ ybuf) {
  const int tid = threadIdx.x, lane = tid & 63, wid = tid >> 6;
  const int l15 = lane & 15, quad = lane >> 4;
  const int m0 = blockIdx.x * 64;
  const int arow = m0 + wid * 16 + l15;

  short8 afrag[4];
#pragma unroll
  for (int kk = 0; kk < 4; ++kk)
    afrag[kk] = *(const short8*)(xb + (size_t)arow * 128 + kk * 32 + quad * 8);

  floatx4 acc[8];
  const floatx4 zero = {0.f, 0.f, 0.f, 0.f};
#pragma unroll
  for (int j = 0; j < 8; ++j) acc[j] = zero;
#pragma unroll
  for (int kk = 0; kk < 4; ++kk) {
    const int koff = kk * 32 + quad * 8;
#pragma unroll
    for (int j = 0; j < 8; ++j) {
      short8 b = *(const short8*)(Bmat + (j * 16 + l15) * 128 + koff);
      acc[j] = __builtin_amdgcn_mfma_f32_16x16x32_bf16(afrag[kk], b, acc[j], 0, 0, 0);
    }
  }
#pragma unroll
  for (int r = 0; r < 4; ++r) {
    int row = m0 + wid * 16 + quad * 4 + r;
    float dv = dinv[row];
#pragma unroll
    for (int j = 0; j < 8; ++j)
      ybuf[(size_t)row * 128 + j * 16 + l15] = f2bf(acc[j][r] * dv);
  }
}

// fused update (bf16 state, barrier-free):
//   GEMM1: s0 = x@Am^T (acc, C-layout) -> per-wave LDS slice -> re-read A-layout
//   epilogue (all A-layout, vectorized): s = s0 + g + bias; h = tanh(s);
//   x' = x + eps*h; store xb (16B), optional out (f32/bf16); a2 = bf16(x')
//   GEMM2 (if ybuf): y = (x'@Wphi^T)*dinv, C-layout write.
__global__ __launch_bounds__(256) void fused_kernel(
    unsigned short* __restrict__ xb, const unsigned short* __restrict__ Am,
    const unsigned short* __restrict__ Wphi, const float* __restrict__ dinv,
    const unsigned short* __restrict__ g, const float* __restrict__ bias_f,
    void* __restrict__ outb, unsigned short* __restrict__ ybuf,
    const int* __restrict__ flag, int Mvalid) {
  __shared__ float accs[64 * ALDP];   // 33792 B, per-wave 16-row slices
  const int tid = threadIdx.x, lane = tid & 63, wid = tid >> 6;
  const int l15 = lane & 15, quad = lane >> 4;
  const int m0 = blockIdx.x * 64;
  const int arow = m0 + wid * 16 + l15;
  const size_t abase = (size_t)arow * 128 + quad * 8;

  short8 afrag[4], gfrag[4];
#pragma unroll
  for (int kk = 0; kk < 4; ++kk) afrag[kk] = *(const short8*)(xb + abase + kk * 32);
#pragma unroll
  for (int kk = 0; kk < 4; ++kk) gfrag[kk] = *(const short8*)(g + abase + kk * 32);

  floatx4 acc[8];
  const floatx4 zero = {0.f, 0.f, 0.f, 0.f};
#pragma unroll
  for (int j = 0; j < 8; ++j) acc[j] = zero;
#pragma unroll
  for (int kk = 0; kk < 4; ++kk) {
    const int koff = kk * 32 + quad * 8;
#pragma unroll
    for (int j = 0; j < 8; ++j) {
      short8 b = *(const short8*)(Am + (j * 16 + l15) * 128 + koff);
      acc[j] = __builtin_amdgcn_mfma_f32_16x16x32_bf16(afrag[kk], b, acc[j], 0, 0, 0);
    }
  }

  // C-layout -> per-wave LDS slice (rows wid*16..wid*16+15; same-wave only)
#pragma unroll
  for (int r = 0; r < 4; ++r) {
    int lrow = wid * 16 + quad * 4 + r;
#pragma unroll
    for (int j = 0; j < 8; ++j)
      accs[lrow * ALDP + j * 16 + l15] = acc[j][r];
  }

  const int isf = *flag;
  const bool valid = arow < Mvalid;
  short8 a2[4];
#pragma unroll
  for (int kk = 0; kk < 4; ++kk) {
    const int col0 = kk * 32 + quad * 8;
    const float* ap = &accs[(wid * 16 + l15) * ALDP + col0];
    float4 s0 = *(const float4*)ap;
    float4 s1 = *(const float4*)(ap + 4);
    float4 b0 = *(const float4*)&bias_f[col0];
    float4 b1 = *(const float4*)&bias_f[col0 + 4];
    union { short8 s; unsigned short h[8]; } xu; xu.s = afrag[kk];
    union { short8 s; unsigned short h[8]; } gu; gu.s = gfrag[kk];
    float xv[8];
    xv[0] = bf2f(xu.h[0]) + EPSILON * tanh_fast(s0.x + bf2f(gu.h[0]) + b0.x);
    xv[1] = bf2f(xu.h[1]) + EPSILON * tanh_fast(s0.y + bf2f(gu.h[1]) + b0.y);
    xv[2] = bf2f(xu.h[2]) + EPSILON * tanh_fast(s0.z + bf2f(gu.h[2]) + b0.z);
    xv[3] = bf2f(xu.h[3]) + EPSILON * tanh_fast(s0.w + bf2f(gu.h[3]) + b0.w);
    xv[4] = bf2f(xu.h[4]) + EPSILON * tanh_fast(s1.x + bf2f(gu.h[4]) + b1.x);
    xv[5] = bf2f(xu.h[5]) + EPSILON * tanh_fast(s1.y + bf2f(gu.h[5]) + b1.y);
    xv[6] = bf2f(xu.h[6]) + EPSILON * tanh_fast(s1.z + bf2f(gu.h[6]) + b1.z);
    xv[7] = bf2f(xu.h[7]) + EPSILON * tanh_fast(s1.w + bf2f(gu.h[7]) + b1.w);
    uint4 pk;
    pk.x = f2_to_bfx2(xv[0], xv[1]); pk.y = f2_to_bfx2(xv[2], xv[3]);
    pk.z = f2_to_bfx2(xv[4], xv[5]); pk.w = f2_to_bfx2(xv[6], xv[7]);
    union { uint4 u; short8 s; } cv; cv.u = pk;
    a2[kk] = cv.s;
    if (valid) {
      *(uint4*)(xb + abase + kk * 32) = pk;
      if (outb) {
        if (isf) {
          float* op = (float*)outb + abase + kk * 32;
          *(float4*)op = make_float4(xv[0], xv[1], xv[2], xv[3]);
          *(float4*)(op + 4) = make_float4(xv[4], xv[5], xv[6], xv[7]);
        } else {
          *(uint4*)((unsigned short*)outb + abase + kk * 32) = pk;
        }
      }
    }
  }

  if (ybuf) {
    floatx4 acc2[8];
#pragma unroll
    for (int j = 0; j < 8; ++j) acc2[j] = zero;
#pragma unroll
    for (int kk = 0; kk < 4; ++kk) {
      const int koff = kk * 32 + quad * 8;
#pragma unroll
      for (int j = 0; j < 8; ++j) {
        short8 b = *(const short8*)(Wphi + (j * 16 + l15) * 128 + koff);
        acc2[j] = __builtin_amdgcn_mfma_f32_16x16x32_bf16(a2[kk], b, acc2[j], 0, 0, 0);
      }
    }
#pragma unroll
    for (int r = 0; r < 4; ++r) {
      int row = m0 + wid * 16 + quad * 4 + r;
      float dv = dinv[row];
#pragma unroll
      for (int j = 0; j < 8; ++j)
        ybuf[(size_t)row * 128 + j * 16 + l15] = f2bf(acc2[j][r] * dv);
    }
  }
}

// one wave per node, quad-per-edge gather
__global__ __launch_bounds__(256) void agg_kernel(
    const unsigned short* __restrict__ y,
    const int* __restrict__ offs,
    const int* __restrict__ csr,
    const float* __restrict__ dinv,
    unsigned short* __restrict__ g,
    int N) {
  int i = blockIdx.x * 4 + (threadIdx.x >> 6);
  if (i >= N) return;
  int lane = threadIdx.x & 63;
  int sub = lane >> 4;
  int c8 = (lane & 15) * 8;

  float a0 = 0.f, a1 = 0.f, a2 = 0.f, a3 = 0.f, a4 = 0.f, a5 = 0.f, a6 = 0.f, a7 = 0.f;

  int e0 = offs[i], e1 = offs[i + 1];
  int e = e0 + sub;
  for (; e + 4 < e1; e += 8) {
    int s0 = csr[e];
    int s1 = csr[e + 4];
    uint4 u0 = *(const uint4*)(y + (size_t)s0 * 128 + c8);
    uint4 u1 = *(const uint4*)(y + (size_t)s1 * 128 + c8);
    float2 f;
    f = bfx2_to_f2(u0.x); a0 += f.x; a1 += f.y;
    f = bfx2_to_f2(u0.y); a2 += f.x; a3 += f.y;
    f = bfx2_to_f2(u0.z); a4 += f.x; a5 += f.y;
    f = bfx2_to_f2(u0.w); a6 += f.x; a7 += f.y;
    f = bfx2_to_f2(u1.x); a0 += f.x; a1 += f.y;
    f = bfx2_to_f2(u1.y); a2 += f.x; a3 += f.y;
    f = bfx2_to_f2(u1.z); a4 += f.x; a5 += f.y;
    f = bfx2_to_f2(u1.w); a6 += f.x; a7 += f.y;
  }
  if (e < e1) {
    int s0 = csr[e];
    uint4 u0 = *(const uint4*)(y + (size_t)s0 * 128 + c8);
    float2 f;
    f = bfx2_to_f2(u0.x); a0 += f.x; a1 += f.y;
    f = bfx2_to_f2(u0.y); a2 += f.x; a3 += f.y;
    f = bfx2_to_f2(u0.z); a4 += f.x; a5 += f.y;
    f = bfx2_to_f2(u0.w); a6 += f.x; a7 += f.y;
  }

  a0 += __shfl_xor(a0, 16, 64); a0 += __shfl_xor(a0, 32, 64);
  a1 += __shfl_xor(a1, 16, 64); a1 += __shfl_xor(a1, 32, 64);
  a2 += __shfl_xor(a2, 16, 64); a2 += __shfl_xor(a2, 32, 64);
  a3 += __shfl_xor(a3, 16, 64); a3 += __shfl_xor(a3, 32, 64);
  a4 += __shfl_xor(a4, 16, 64); a4 += __shfl_xor(a4, 32, 64);
  a5 += __shfl_xor(a5, 16, 64); a5 += __shfl_xor(a5, 32, 64);
  a6 += __shfl_xor(a6, 16, 64); a6 += __shfl_xor(a6, 32, 64);
  a7 += __shfl_xor(a7, 16, 64); a7 += __shfl_xor(a7, 32, 64);

  if (sub == 0) {
    uint4 su = *(const uint4*)(y + (size_t)i * 128 + c8);
    float2 f;
    f = bfx2_to_f2(su.x); a0 += f.x; a1 += f.y;
    f = bfx2_to_f2(su.y); a2 += f.x; a3 += f.y;
    f = bfx2_to_f2(su.z); a4 += f.x; a5 += f.y;
    f = bfx2_to_f2(su.w); a6 += f.x; a7 += f.y;
    float dv = dinv[i];
    uint4 o;
    o.x = f2_to_bfx2(a0 * dv, a1 * dv);
    o.y = f2_to_bfx2(a2 * dv, a3 * dv);
    o.z = f2_to_bfx2(a4 * dv, a5 * dv);
    o.w = f2_to_bfx2(a6 * dv, a7 * dv);
    *(uint4*)(g + (size_t)i * 128 + c8) = o;
  }
}

// ------------------------------------------------------------- launch

extern "C" void kernel_launch(void* const* d_in, const int* in_sizes, int n_in,
                              void* d_out, int out_size, void* d_ws, size_t ws_size,
                              hipStream_t stream) {
  const void* x_in = d_in[0];
  const int* ei = (const int*)d_in[1];
  const void* W = d_in[2];
  const void* Wphi = d_in[3];
  const void* bias = d_in[4];

  const int N = in_sizes[0] / 128;
  const int E = in_sizes[1] / 2;
  const int NP = ((N + 63) / 64) * 64;
  const int* src = ei;
  const int* dst = ei + E;
  const int NB = (N + 511) >> BSHIFT;
  const int EB = (E + 4095) / 4096;

  size_t off = 0;
  auto place = [&](size_t bytes) { size_t r = off; off = (off + bytes + 255) & ~(size_t)255; return r; };
  size_t o_xb   = place((size_t)NP * 128 * 2);
  size_t o_y    = place((size_t)NP * 128 * 2);
  size_t o_g    = place((size_t)NP * 128 * 2);
  size_t o_Am   = place(128 * 128 * 2);
  size_t o_Wb   = place(128 * 128 * 2);
  size_t o_bf   = place(128 * 4);
  size_t o_flag = place(4);
  size_t o_dinv = place((size_t)(NB * 512 + 64) * 4);
  size_t o_offs = place((size_t)(N + 1) * 4);
  size_t o_gcnt = place((size_t)NB * 4);
  size_t o_gofs = place((size_t)(NB + 1) * 4);
  size_t o_gcur = place((size_t)NB * 4);
  size_t o_bprs = place((size_t)E * 8);
  size_t o_csr  = place((size_t)E * 4);
  if (off > ws_size || in_sizes[0] % 128 != 0 || out_size != N * 128 || n_in < 5) {
    fill_kernel<<<(out_size * 2 + 255) / 256, 256, 0, stream>>>(
        (unsigned short*)d_out, out_size, (unsigned short)0x3F80);
    return;
  }
  char* basep = (char*)d_ws;
  unsigned short* xb = (unsigned short*)(basep + o_xb);
  unsigned short* y  = (unsigned short*)(basep + o_y);
  unsigned short* g  = (unsigned short*)(basep + o_g);
  unsigned short* Am = (unsigned short*)(basep + o_Am);
  unsigned short* Wb = (unsigned short*)(basep + o_Wb);
  float* bias_f = (float*)(basep + o_bf);
  int* flag   = (int*)(basep + o_flag);
  float* dinv = (float*)(basep + o_dinv);
  int* offs   = (int*)(basep + o_offs);
  int* gcnt   = (int*)(basep + o_gcnt);
  int* gofs   = (int*)(basep + o_gofs);
  int* gcur   = (int*)(basep + o_gcur);
  uint2* bpairs = (uint2*)(basep + o_bprs);
  int* csr    = (int*)(basep + o_csr);

  hipMemsetAsync(gcnt, 0, (size_t)NB * 4, stream);
  detect_kernel<<<1, 256, 0, stream>>>((const unsigned int*)x_in, flag);
  prep_kernel<<<(128 * 128 + 255) / 256, 256, 0, stream>>>(W, Wphi, bias, flag, Am, Wb, bias_f);
  init_x_kernel<<<(NP * 16 + 255) / 256, 256, 0, stream>>>(x_in, flag, xb, N, NP);
  bcount_kernel<<<EB, 256, 0, stream>>>(dst, gcnt, E, NB);
  bscan_kernel<<<1, 64, 0, stream>>>(gcnt, gofs, gcur, NB, E);
  bscatter_kernel<<<EB, 256, 0, stream>>>(src, dst, gcur, bpairs, E, NB);
  bfinal_kernel<<<NB, 256, 0, stream>>>(bpairs, gofs, offs, dinv, csr, N, NP, E);

  const int gblocks = NP / 64;
  gemm0_kernel<<<gblocks, 256, 0, stream>>>(xb, Wb, dinv, y);
  for (int t = 0; t < NUM_ITERS; ++t) {
    agg_kernel<<<(N + 3) / 4, 256, 0, stream>>>(y, offs, csr, dinv, g, N);
    void* outp = (t == NUM_ITERS - 1) ? d_out : nullptr;
    unsigned short* ynext = (t == NUM_ITERS - 1) ? nullptr : y;
    fused_kernel<<<gblocks, 256, 0, stream>>>(xb, Am, Wb, dinv, g, bias_f,
                                              outp, ynext, flag, N);
  }
}